// Round 11
// baseline (203.863 us; speedup 1.0000x reference)
//
#include <hip/hip_runtime.h>
#include <hip/hip_bf16.h>
#include <stdint.h>

// Problem constants (S=1024, B=2 -> T=2048 tokens)
#define TT 2048
#define DD 512
#define FF 2048
#define EE 8

typedef unsigned short u16;
typedef __attribute__((ext_vector_type(8))) unsigned short ushort8v;
typedef __attribute__((ext_vector_type(8))) short short8;     // bf16x8 frag
typedef __attribute__((ext_vector_type(4))) float float4v;

__device__ __forceinline__ u16 f2bf(float f) {
    unsigned u = __float_as_uint(f);
    u += 0x7FFF + ((u >> 16) & 1);   // round-to-nearest-even
    return (u16)(u >> 16);
}

__device__ __forceinline__ void gl_lds16(const u16* g, u16* l) {
    __builtin_amdgcn_global_load_lds(
        (const __attribute__((address_space(1))) unsigned int*)g,
        (__attribute__((address_space(3))) unsigned int*)l, 16, 0, 0);
}

// ---------------- workspace layout (bytes) ----------------
#define WS_HB   0ull                                // hbuf bf16 [6144][2048]
#define WS_XG   (WS_HB + 6144ull*2048*2)            // xg bf16 [2048][512]
#define WS_WT1  (WS_XG + 2048ull*512*2)             // W1t bf16 [9][F][D]
#define WS_ME   (WS_WT1 + 9ull*2048*512*2)          // int  metaE[4096]
#define WS_MW   (WS_ME + 16384)                     // float metaW[4096]
#define WS_RT   (WS_MW + 16384)                     // int  rtok[4096]
#define WS_WROW (WS_RT + 16384)                     // float wrow[4096]
#define WS_TROW (WS_WROW + 16384)                   // int  trow[4096]
#define WS_RTG  (WS_TROW + 16384)                   // routing int[16] = offs[8],cnt[8]
#define WS_WT2  (WS_RTG + 128)                      // W2t bf16 [9][D][F]
#define WS_YB   (WS_WT2 + 9ull*2048*512*2)          // ybuf f32 [6144][512] (single plane)
#define YS      (6144ull*512)
#define WS_NEED (WS_YB + 2ull*6144*512*4)           // ~90.4 MB (ws is 256 MiB)

// ---------------- conv unit: fp32 [R][C] 64x64 tile -> bf16 [C][R] ----------------
// float4 global reads (R7 lesson: scalar strided reads cost more than LDS write
// conflicts). LDS write scatter 8-way -> 4-way via row-XOR swizzle:
// rr' = rr ^ (((col>>2)&3)<<4); bijective per column, phase-2 8-run stays
// 16B-contiguous (XOR touches bits 4-5 only).
__device__ __forceinline__ void conv_unit(int j, const float* __restrict__ srcE,
                                          const float* __restrict__ srcS,
                                          u16* __restrict__ dst,
                                          int R, int C, int shC, u16* Ls) {
    int mid = j >> 8, t2 = j & 255;
    int tr = t2 >> shC, tc = t2 & ((1 << shC) - 1);
    int r0 = tr * 64, c0 = tc * 64;
    const float* src = (mid < 8) ? srcE + (size_t)mid * R * C : srcS;
    u16* dstm = dst + (size_t)mid * R * C;
    int t = threadIdx.x;
#pragma unroll
    for (int i = 0; i < 4; ++i) {
        int rr = (t >> 4) + i * 16;
        int cc = (t & 15) * 4;
        float4v v = *(const float4v*)(src + (size_t)(r0 + rr) * C + c0 + cc);
#pragma unroll
        for (int jx = 0; jx < 4; ++jx) {
            int c = cc + jx;
            int rs = rr ^ (((c >> 2) & 3) << 4);
            Ls[c * 72 + rs] = f2bf(v[jx]);
        }
    }
    __syncthreads();
#pragma unroll
    for (int jj = 0; jj < 2; ++jj) {
        int slot = t + jj * 256;
        int cc = slot >> 3, r8 = (slot & 7) * 8;
        int r8s = r8 ^ (((cc >> 2) & 3) << 4);
        ushort8v o = *(const ushort8v*)&Ls[cc * 72 + r8s];
        *(ushort8v*)(dstm + (size_t)(c0 + cc) * R + r0 + r8) = o;
    }
}

// ---------------- gate: one wave per token (fp32 logits = np ref) ----------------
__device__ __forceinline__ void gate_wave(int t, int lane,
                                          const float* __restrict__ x,
                                          const float* __restrict__ Wg,
                                          const float* __restrict__ bg,
                                          int* __restrict__ metaE,
                                          float* __restrict__ metaW,
                                          u16* __restrict__ xg) {
    const float* xp = x + (size_t)t * DD + lane * 8;
    float4v x0 = *(const float4v*)xp;
    float4v x1 = *(const float4v*)(xp + 4);
    float xf[8] = {x0[0], x0[1], x0[2], x0[3], x1[0], x1[1], x1[2], x1[3]};
    float acc[EE] = {0.f, 0.f, 0.f, 0.f, 0.f, 0.f, 0.f, 0.f};
#pragma unroll
    for (int g = 0; g < 8; ++g) {
        const float* wp = Wg + (size_t)(lane * 8 + g) * EE;
        float4v w0 = *(const float4v*)wp;
        float4v w1 = *(const float4v*)(wp + 4);
        acc[0] += xf[g] * w0[0]; acc[1] += xf[g] * w0[1];
        acc[2] += xf[g] * w0[2]; acc[3] += xf[g] * w0[3];
        acc[4] += xf[g] * w1[0]; acc[5] += xf[g] * w1[1];
        acc[6] += xf[g] * w1[2]; acc[7] += xf[g] * w1[3];
    }
#pragma unroll
    for (int off = 1; off < 64; off <<= 1) {
#pragma unroll
        for (int e = 0; e < EE; ++e) acc[e] += __shfl_xor(acc[e], off, 64);
    }
    ushort8v xv;
#pragma unroll
    for (int jx = 0; jx < 4; ++jx) xv[jx] = f2bf(x0[jx]);
#pragma unroll
    for (int jx = 0; jx < 4; ++jx) xv[4 + jx] = f2bf(x1[jx]);
    *(ushort8v*)(xg + (size_t)t * DD + lane * 8) = xv;
    if (lane == 0) {
#pragma unroll
        for (int e = 0; e < EE; ++e) acc[e] += bg[e];
        int e0 = 0; float l0 = acc[0];
#pragma unroll
        for (int e = 1; e < EE; ++e) if (acc[e] > l0) { l0 = acc[e]; e0 = e; }
        int e1 = -1; float l1 = -3.4e38f;
#pragma unroll
        for (int e = 0; e < EE; ++e)
            if (e != e0 && acc[e] > l1) { l1 = acc[e]; e1 = e; }
        float ex = __expf(l1 - l0);
        float w0 = 1.f / (1.f + ex);
        metaE[2 * t] = e0; metaE[2 * t + 1] = e1;
        metaW[2 * t] = w0; metaW[2 * t + 1] = 1.f - w0;
    }
}

// ---------------- fused phase-1: conv1 + conv2 + gate (+ out-zero for !big) ------
__global__ __launch_bounds__(256) void fused1_k(
    const float* __restrict__ x, const float* __restrict__ Wg,
    const float* __restrict__ bg,
    const float* __restrict__ W1, const float* __restrict__ Ws1,
    const float* __restrict__ W2, const float* __restrict__ Ws2,
    float* __restrict__ out, u16* __restrict__ xg,
    u16* __restrict__ Wt1, u16* __restrict__ Wt2,
    int* __restrict__ metaE, float* __restrict__ metaW, int nconv) {
    __shared__ __align__(16) u16 Ls[64 * 72];
    int b = blockIdx.x, tid = threadIdx.x;
    if (b < nconv) {
        if (b < 2304) conv_unit(b, W1, Ws1, Wt1, DD, FF, 5, Ls);
        else          conv_unit(b - 2304, W2, Ws2, Wt2, FF, DD, 3, Ls);
    } else if (b < nconv + 512) {
        int gb = b - nconv;
        gate_wave(gb * 4 + (tid >> 6), tid & 63, x, Wg, bg, metaE, metaW, xg);
    } else {
        int zb = b - nconv - 512;
        float* op = out + (size_t)zb * 8192;
#pragma unroll
        for (int it = 0; it < 8; ++it)
            *(float4v*)(op + it * 1024 + tid * 4) = (float4v){0.f, 0.f, 0.f, 0.f};
    }
}

__global__ __launch_bounds__(256) void conv2_k(const float* __restrict__ W2,
                                               const float* __restrict__ Ws2,
                                               u16* __restrict__ Wt2) {
    __shared__ __align__(16) u16 Ls[64 * 72];
    conv_unit(blockIdx.x, W2, Ws2, Wt2, FF, DD, 3, Ls);
}

// ---------------- rank: 1 block x 256, ballot-based, 0 atomics ----------------
__global__ __launch_bounds__(256) void rank_k(const int* __restrict__ metaE,
                                              const float* __restrict__ metaW,
                                              int* __restrict__ routing,
                                              int* __restrict__ rtok,
                                              float* __restrict__ wrow,
                                              int* __restrict__ trow) {
    __shared__ __align__(16) char smem[16384];
    u16* er      = (u16*)smem;
    int* segCnt  = (int*)(smem + 8192);
    int* segBase = (int*)(smem + 10240);
    int* expTot  = (int*)(smem + 12288);
    int tid = threadIdx.x, wv = tid >> 6, lane = tid & 63;
    unsigned long long below = (lane == 0) ? 0ull : ((~0ull) >> (64 - lane));
    for (int s = wv * 16; s < wv * 16 + 16; ++s) {
        int entry = s * 64 + lane;
        int e = metaE[entry];
        int rk = 0;
#pragma unroll
        for (int ee = 0; ee < 8; ++ee) {
            unsigned long long m = __ballot(e == ee);
            if (e == ee) rk = __popcll(m & below);
            if (lane == ee) segCnt[s * 8 + ee] = __popcll(m);
        }
        er[entry] = (u16)(e | (rk << 4));
    }
    __syncthreads();
    if (tid < 8) {
        int s = 0;
        for (int g = 0; g < 64; ++g) { segBase[g * 8 + tid] = s; s += segCnt[g * 8 + tid]; }
        expTot[tid] = s;
    }
    __syncthreads();
    if (tid == 0) {
        int s = 0;
        for (int e = 0; e < 8; ++e) { int c = expTot[e]; expTot[8 + e] = s; s += c; }
    }
    __syncthreads();
    if (tid < 8) { routing[tid] = expTot[8 + tid]; routing[8 + tid] = expTot[tid]; }
    for (int i = 0; i < 16; ++i) {
        int entry = tid + i * 256;
        int v = er[entry];
        int e = v & 15, rk = v >> 4;
        int row = expTot[8 + e] + segBase[(entry >> 6) * 8 + e] + rk;
        rtok[row] = entry >> 1;
        wrow[row] = metaW[entry];
        trow[entry] = row;             // inverse map: token*2+k -> sorted row
    }
}

// ---------------- GEMM A: BM=128,BN=128,BK=64, 8 waves, dbuf 2-phase -------------
// R10 structure (best measured) with LDS-coalesced C-epilogue. Untouched.
// jobs: [0,256) shared (rt4|ct4); [256,4352): jr = (rt*16+ct)*8 + e (e=XCD pin).
__global__ __launch_bounds__(512) void gemmA_k(
    const u16* __restrict__ xg, const u16* __restrict__ Wt1,
    const float* __restrict__ b1, const float* __restrict__ bs1,
    const int* __restrict__ routing, const int* __restrict__ rtok,
    u16* __restrict__ hbuf) {
    __shared__ __align__(16) u16 SM[32768];          // 64 KB
    u16* Asb[2] = {SM, SM + 8192};                   // 2 x [128][64]
    u16* Bsb[2] = {SM + 16384, SM + 24576};          // 2 x [128][64]
    const int* offs = routing; const int* cnt = routing + 8;
    int j = blockIdx.x, tid = threadIdx.x;
    int rt, ct, Mloc, hRowBase, rowBase; bool routed;
    const u16* Bsrc; const float* bias;
    if (j < 256) {
        rt = j >> 4; ct = j & 15; Mloc = 128; rowBase = rt * 128;
        Bsrc = Wt1 + (size_t)8 * FF * DD; bias = bs1;
        hRowBase = 4096 + rt * 128; routed = false;
    } else {
        int jr = j - 256; int e = jr & 7; int rc = jr >> 3;
        rt = rc >> 4; ct = rc & 15;
        int M = cnt[e]; if (rt * 128 >= M) return;
        Mloc = M - rt * 128; if (Mloc > 128) Mloc = 128;
        rowBase = offs[e] + rt * 128;
        Bsrc = Wt1 + (size_t)e * FF * DD; bias = b1 + e * FF;
        hRowBase = rowBase; routed = true;
    }
    int n0 = ct * 128;
    int lane = tid & 63, w = tid >> 6, ln = lane & 15, quad = lane >> 4;
    int wm = w >> 2, wn = w & 3;         // 2x4 wave grid
    int lr8 = lane >> 3;
    int cs = (lane & 7) ^ lr8;           // pre-swizzled source chunk
    const u16* ApS[2];
#pragma unroll
    for (int i = 0; i < 2; ++i) {
        int r = w * 16 + i * 8 + lr8;    // 0..127
        int tok;
        if (routed) { int br = rowBase + r; if (br > 4095) br = 4095; tok = rtok[br]; }
        else tok = rowBase + r;
        ApS[i] = xg + (size_t)tok * DD + cs * 8;
    }
    const u16* BpS[2];
#pragma unroll
    for (int i = 0; i < 2; ++i) {
        int r = w * 16 + i * 8 + lr8;
        BpS[i] = Bsrc + (size_t)(n0 + r) * DD + cs * 8;
    }
    float4v acc[4][2];
#pragma unroll
    for (int a = 0; a < 4; ++a)
#pragma unroll
        for (int b = 0; b < 2; ++b) acc[a][b] = (float4v){0.f, 0.f, 0.f, 0.f};

    auto stage = [&](int kt, int pb) {
#pragma unroll
        for (int i = 0; i < 2; ++i)
            gl_lds16(ApS[i] + kt * 64, Asb[pb] + (w * 16 + i * 8) * 64);
#pragma unroll
        for (int i = 0; i < 2; ++i)
            gl_lds16(BpS[i] + kt * 64, Bsb[pb] + (w * 16 + i * 8) * 64);
    };

    stage(0, 0);
#pragma unroll
    for (int kt = 0; kt < 8; ++kt) {
        int pb = kt & 1;
        if (kt < 7) {
            stage(kt + 1, pb ^ 1);
            asm volatile("s_waitcnt vmcnt(4)" ::: "memory");
        } else {
            asm volatile("s_waitcnt vmcnt(0)" ::: "memory");
        }
        __builtin_amdgcn_s_barrier();
        __builtin_amdgcn_sched_barrier(0);
        const u16* Ab = Asb[pb]; const u16* Bb = Bsb[pb];
#pragma unroll
        for (int s = 0; s < 2; ++s) {
            int chs = ((s * 4 + quad) ^ (ln & 7)) * 8;
            short8 Af[4], Bf[2];
#pragma unroll
            for (int a = 0; a < 4; ++a) {
                int ra = wm * 64 + a * 16 + ln;
                Af[a] = *(const short8*)(Ab + ra * 64 + chs);
            }
#pragma unroll
            for (int b = 0; b < 2; ++b) {
                int rb = wn * 32 + b * 16 + ln;
                Bf[b] = *(const short8*)(Bb + rb * 64 + chs);
            }
#pragma unroll
            for (int a = 0; a < 4; ++a)
#pragma unroll
                for (int b = 0; b < 2; ++b)
                    acc[a][b] = __builtin_amdgcn_mfma_f32_16x16x32_bf16(Af[a], Bf[b], acc[a][b], 0, 0, 0);
        }
        __builtin_amdgcn_sched_barrier(0);
        __builtin_amdgcn_s_barrier();
    }
    // ---- LDS-coalesced epilogue: acc -> Cs[128][136] -> 256B-row stores ----
    __syncthreads();                     // all LDS reads of As/Bs done
    u16* Cs = SM;                        // 128*136 u16 = 34.8 KB (dead buffers)
#pragma unroll
    for (int b = 0; b < 2; ++b) {
        int n = wn * 32 + b * 16 + ln;
        float bv = bias[n0 + n];
#pragma unroll
        for (int a = 0; a < 4; ++a) {
#pragma unroll
            for (int i = 0; i < 4; ++i) {
                int lr = wm * 64 + a * 16 + quad * 4 + i;
                float v = acc[a][b][i] + bv;
                v = v > 0.f ? v : 0.f;
                Cs[lr * 136 + n] = f2bf(v);
            }
        }
    }
    __syncthreads();
#pragma unroll
    for (int p = 0; p < 4; ++p) {
        int idx = p * 512 + tid;         // 2048 chunks of 16B
        int row = idx >> 4, ch = idx & 15;
        if (row < Mloc) {
            ushort8v o = *(const ushort8v*)(Cs + row * 136 + ch * 8);
            *(ushort8v*)(hbuf + (size_t)(hRowBase + row) * FF + n0 + ch * 8) = o;
        }
    }
}

// ---------------- GEMM B (big): BM=128,BN=128,BK=64, FULL K=2048, NO ksplit ------
// Single ybuf plane (halves ybuf write + combine read traffic vs ksplit x2).
// 192 active blocks at 2/CU -> still fully co-resident.
// jobs: [0,64) shared (rt4|ct2); [64,1088): jr = (rt*4+ct)*8 + e (rt<32 safety).
__global__ __launch_bounds__(512) void gemmB_k(
    const u16* __restrict__ hbuf, const u16* __restrict__ Wt2,
    const float* __restrict__ b2, const float* __restrict__ bs2,
    const int* __restrict__ routing, float* __restrict__ ybuf) {
    __shared__ __align__(16) u16 As[2][128 * 64];    // 2 x 16 KB
    __shared__ __align__(16) u16 Bs[2][128 * 64];    // 2 x 16 KB
    const int* offs = routing; const int* cnt = routing + 8;
    int j = blockIdx.x, tid = threadIdx.x;
    int rt, ct, Mloc, aRowBase;
    const u16* Bsrc; const float* bias;
    if (j < 64) {
        rt = j >> 2; ct = j & 3;
        Mloc = 128; aRowBase = 4096 + rt * 128;
        Bsrc = Wt2 + (size_t)8 * DD * FF; bias = bs2;
    } else {
        int jr = j - 64; int e = jr & 7; int rc = jr >> 3;
        ct = rc & 3; rt = rc >> 2;
        int M = cnt[e]; if (rt * 128 >= M) return;
        Mloc = M - rt * 128; if (Mloc > 128) Mloc = 128;
        aRowBase = offs[e] + rt * 128;
        Bsrc = Wt2 + (size_t)e * DD * FF; bias = b2 + e * DD;
    }
    int n0 = ct * 128;
    int lane = tid & 63, w = tid >> 6, ln = lane & 15, quad = lane >> 4;
    int wm = w >> 2, wn = w & 3;
    int lr8 = lane >> 3;
    int cs = (lane & 7) ^ lr8;
    const u16* ApS[2];
#pragma unroll
    for (int i = 0; i < 2; ++i) {
        int r = w * 16 + i * 8 + lr8;
        ApS[i] = hbuf + (size_t)(aRowBase + r) * FF + cs * 8;
    }
    const u16* BpS[2];
#pragma unroll
    for (int i = 0; i < 2; ++i) {
        int r = w * 16 + i * 8 + lr8;
        BpS[i] = Bsrc + (size_t)(n0 + r) * FF + cs * 8;
    }
    float4v acc[4][2];
#pragma unroll
    for (int a = 0; a < 4; ++a)
#pragma unroll
        for (int b = 0; b < 2; ++b) acc[a][b] = (float4v){0.f, 0.f, 0.f, 0.f};

    auto stage = [&](int kt, int pb) {
#pragma unroll
        for (int i = 0; i < 2; ++i)
            gl_lds16(ApS[i] + kt * 64, &As[pb][0] + (w * 16 + i * 8) * 64);
#pragma unroll
        for (int i = 0; i < 2; ++i)
            gl_lds16(BpS[i] + kt * 64, &Bs[pb][0] + (w * 16 + i * 8) * 64);
    };

    stage(0, 0);
#pragma unroll
    for (int kt = 0; kt < 32; ++kt) {
        int pb = kt & 1;
        if (kt < 31) {
            stage(kt + 1, pb ^ 1);
            asm volatile("s_waitcnt vmcnt(4)" ::: "memory");
        } else {
            asm volatile("s_waitcnt vmcnt(0)" ::: "memory");
        }
        __builtin_amdgcn_s_barrier();
        __builtin_amdgcn_sched_barrier(0);
        const u16* Ab = &As[pb][0]; const u16* Bb = &Bs[pb][0];
#pragma unroll
        for (int s = 0; s < 2; ++s) {
            int chs = ((s * 4 + quad) ^ (ln & 7)) * 8;
            short8 Af[4], Bf[2];
#pragma unroll
            for (int a = 0; a < 4; ++a) {
                int ra = wm * 64 + a * 16 + ln;
                Af[a] = *(const short8*)(Ab + ra * 64 + chs);
            }
#pragma unroll
            for (int b = 0; b < 2; ++b) {
                int rb = wn * 32 + b * 16 + ln;
                Bf[b] = *(const short8*)(Bb + rb * 64 + chs);
            }
#pragma unroll
            for (int a = 0; a < 4; ++a)
#pragma unroll
                for (int b = 0; b < 2; ++b)
                    acc[a][b] = __builtin_amdgcn_mfma_f32_16x16x32_bf16(Af[a], Bf[b], acc[a][b], 0, 0, 0);
        }
        __builtin_amdgcn_sched_barrier(0);
        __builtin_amdgcn_s_barrier();
    }
#pragma unroll
    for (int b = 0; b < 2; ++b) {
        int n = n0 + wn * 32 + b * 16 + ln;
        float bv = bias[n];
#pragma unroll
        for (int a = 0; a < 4; ++a) {
#pragma unroll
            for (int i = 0; i < 4; ++i) {
                int lr = wm * 64 + a * 16 + quad * 4 + i;
                if (lr < Mloc)
                    ybuf[(size_t)(aRowBase + lr) * DD + n] = acc[a][b][i] + bv;
            }
        }
    }
}

// ---------------- combine: out[t] = w0*y[r0] + w1*y[r1] + 0.5*y[4096+t] ----------
__global__ __launch_bounds__(256) void combine_k(
    const float* __restrict__ ybuf, const int* __restrict__ trow,
    const float* __restrict__ metaW, float* __restrict__ out) {
    int tid = threadIdx.x;
    int tok = blockIdx.x * 2 + (tid >> 7);
    int q = (tid & 127) * 4;
    int r0 = trow[2 * tok], r1 = trow[2 * tok + 1];
    float w0 = metaW[2 * tok], w1 = metaW[2 * tok + 1];
    float4v y0 = *(const float4v*)(ybuf + (size_t)r0 * DD + q);
    float4v y1 = *(const float4v*)(ybuf + (size_t)r1 * DD + q);
    float4v ys = *(const float4v*)(ybuf + (size_t)(4096 + tok) * DD + q);
    float4v o;
#pragma unroll
    for (int i = 0; i < 4; ++i) o[i] = w0 * y0[i] + w1 * y1[i] + 0.5f * ys[i];
    *(float4v*)(out + (size_t)tok * DD + q) = o;
}

// ---------------- GEMM B (!big fallback): K-split x2, pipelined, atomics --------
__global__ __launch_bounds__(256) void gemmBat_k(
    const u16* __restrict__ hbuf, const u16* __restrict__ Wt2,
    const float* __restrict__ b2, const float* __restrict__ bs2,
    const int* __restrict__ routing, const int* __restrict__ rtok,
    const float* __restrict__ wrow, float* __restrict__ out) {
    __shared__ __align__(16) u16 As[2][64 * 64];
    __shared__ __align__(16) u16 Bs[2][128 * 64];
    const int* offs = routing; const int* cnt = routing + 8;
    int j = blockIdx.x, tid = threadIdx.x;
    int rt, ct, ks, Mloc, aRowBase; bool sh;
    const u16* Bsrc; const float* bias;
    if (j < 256) {
        sh = true; rt = j >> 3; int sub = j & 7; ct = sub >> 1; ks = sub & 1;
        Mloc = 64; aRowBase = 4096 + rt * 64;
        Bsrc = Wt2 + (size_t)8 * DD * FF; bias = bs2;
    } else {
        sh = false; int jr = j - 256; int e = jr & 7; int rc = jr >> 3;
        rt = rc >> 3; ct = (rc >> 1) & 3; ks = rc & 1;
        int M = cnt[e]; if (rt * 64 >= M) return;
        Mloc = M - rt * 64; if (Mloc > 64) Mloc = 64;
        aRowBase = offs[e] + rt * 64;
        Bsrc = Wt2 + (size_t)e * DD * FF; bias = b2 + e * DD;
    }
    int n0 = ct * 128;
    int lane = tid & 63, w = tid >> 6, ln = lane & 15, quad = lane >> 4;
    int lr8 = lane >> 3;
    int cs = (lane & 7) ^ lr8;
    const u16* ApS[2];
#pragma unroll
    for (int i = 0; i < 2; ++i) {
        int r = w * 16 + i * 8 + lr8;
        ApS[i] = hbuf + (size_t)(aRowBase + r) * FF + ks * 1024 + cs * 8;
    }
    const u16* BpS[4];
#pragma unroll
    for (int i = 0; i < 4; ++i) {
        int r = w * 32 + i * 8 + lr8;
        BpS[i] = Bsrc + (size_t)(n0 + r) * FF + ks * 1024 + cs * 8;
    }
    float4v acc[2][4];
#pragma unroll
    for (int a = 0; a < 2; ++a)
#pragma unroll
        for (int b = 0; b < 4; ++b) acc[a][b] = (float4v){0.f, 0.f, 0.f, 0.f};
    auto stage = [&](int kt, int pb) {
        u16* Ab = &As[pb][0]; u16* Bb = &Bs[pb][0];
#pragma unroll
        for (int i = 0; i < 2; ++i)
            gl_lds16(ApS[i] + kt * 64, Ab + (w * 16 + i * 8) * 64);
#pragma unroll
        for (int i = 0; i < 4; ++i)
            gl_lds16(BpS[i] + kt * 64, Bb + (w * 32 + i * 8) * 64);
    };
    stage(0, 0);
#pragma unroll
    for (int kt = 0; kt < 16; ++kt) {
        int pb = kt & 1;
        if (kt < 15) {
            stage(kt + 1, pb ^ 1);
            asm volatile("s_waitcnt vmcnt(6)" ::: "memory");
        } else {
            asm volatile("s_waitcnt vmcnt(0)" ::: "memory");
        }
        __builtin_amdgcn_s_barrier();
        __builtin_amdgcn_sched_barrier(0);
        const u16* Ab = &As[pb][0]; const u16* Bb = &Bs[pb][0];
#pragma unroll
        for (int s = 0; s < 2; ++s) {
            int chs = ((s * 4 + quad) ^ (ln & 7)) * 8;
            short8 Af[2], Bf[4];
#pragma unroll
            for (int a = 0; a < 2; ++a) {
                int ra = (w & 1) * 32 + a * 16 + ln;
                Af[a] = *(const short8*)(Ab + ra * 64 + chs);
            }
#pragma unroll
            for (int b = 0; b < 4; ++b) {
                int rb = (w >> 1) * 64 + b * 16 + ln;
                Bf[b] = *(const short8*)(Bb + rb * 64 + chs);
            }
#pragma unroll
            for (int a = 0; a < 2; ++a)
#pragma unroll
                for (int b = 0; b < 4; ++b)
                    acc[a][b] = __builtin_amdgcn_mfma_f32_16x16x32_bf16(Af[a], Bf[b], acc[a][b], 0, 0, 0);
        }
        __builtin_amdgcn_sched_barrier(0);
        __builtin_amdgcn_s_barrier();
    }
    float bv[4];
#pragma unroll
    for (int b = 0; b < 4; ++b)
        bv[b] = (ks == 0) ? bias[n0 + (w >> 1) * 64 + b * 16 + ln] : 0.f;
#pragma unroll
    for (int a = 0; a < 2; ++a) {
#pragma unroll
        for (int i = 0; i < 4; ++i) {
            int lr = (w & 1) * 32 + a * 16 + quad * 4 + i;
            if (lr < Mloc) {
                int row = aRowBase + lr;
                int t; float wr;
                if (sh) { t = row - 4096; wr = 0.5f; }
                else    { t = rtok[row]; wr = wrow[row]; }
                float* op = out + (size_t)t * DD;
#pragma unroll
                for (int b = 0; b < 4; ++b) {
                    int n = n0 + (w >> 1) * 64 + b * 16 + ln;
                    atomicAdd(op + n, wr * (acc[a][b][i] + bv[b]));
                }
            }
        }
    }
}

// ---------------- launcher ----------------
extern "C" void kernel_launch(void* const* d_in, const int* in_sizes, int n_in,
                              void* d_out, int out_size, void* d_ws, size_t ws_size,
                              hipStream_t stream) {
    const float* x   = (const float*)d_in[0];
    const float* Wg  = (const float*)d_in[1];
    const float* bg  = (const float*)d_in[2];
    const float* W1  = (const float*)d_in[3];
    const float* b1  = (const float*)d_in[4];
    const float* W2  = (const float*)d_in[5];
    const float* b2  = (const float*)d_in[6];
    const float* Ws1 = (const float*)d_in[7];
    const float* bs1 = (const float*)d_in[8];
    const float* Ws2 = (const float*)d_in[9];
    const float* bs2 = (const float*)d_in[10];
    float* out = (float*)d_out;

    char* ws = (char*)d_ws;
    u16*   hbuf    = (u16*)(ws + WS_HB);
    u16*   xg      = (u16*)(ws + WS_XG);
    u16*   Wt1     = (u16*)(ws + WS_WT1);
    int*   metaE   = (int*)(ws + WS_ME);
    float* metaW   = (float*)(ws + WS_MW);
    int*   rtok    = (int*)(ws + WS_RT);
    float* wrow    = (float*)(ws + WS_WROW);
    int*   trow    = (int*)(ws + WS_TROW);
    int*   routing = (int*)(ws + WS_RTG);
    bool   big     = ws_size >= WS_NEED;
    u16*   Wt2     = big ? (u16*)(ws + WS_WT2) : Wt1;
    float* ybuf    = (float*)(ws + WS_YB);
    int    nconv   = big ? 4608 : 2304;
    int    ngrid1  = big ? (nconv + 512) : (nconv + 640); // zero-jobs only if atomics

    fused1_k<<<ngrid1, 256, 0, stream>>>(x, Wg, bg, W1, Ws1, W2, Ws2,
                                         out, xg, Wt1, Wt2, metaE, metaW, nconv);
    rank_k<<<1, 256, 0, stream>>>(metaE, metaW, routing, rtok, wrow, trow);
    gemmA_k<<<4352, 512, 0, stream>>>(xg, Wt1, b1, bs1, routing, rtok, hbuf);
    if (big) {
        gemmB_k<<<1088, 512, 0, stream>>>(hbuf, Wt2, b2, bs2, routing, ybuf);
        combine_k<<<1024, 256, 0, stream>>>(ybuf, trow, metaW, out);
    } else {
        conv2_k<<<2304, 256, 0, stream>>>(W2, Ws2, Wt2);
        gemmBat_k<<<4352, 256, 0, stream>>>(hbuf, Wt2, b2, bs2, routing, rtok, wrow, out);
    }
}

// Round 12
// 196.056 us; speedup vs baseline: 1.0398x; 1.0398x over previous
//
#include <hip/hip_runtime.h>
#include <hip/hip_bf16.h>
#include <stdint.h>

// Problem constants (S=1024, B=2 -> T=2048 tokens)
#define TT 2048
#define DD 512
#define FF 2048
#define EE 8

typedef unsigned short u16;
typedef __attribute__((ext_vector_type(8))) unsigned short ushort8v;
typedef __attribute__((ext_vector_type(8))) short short8;     // bf16x8 frag
typedef __attribute__((ext_vector_type(4))) float float4v;

__device__ __forceinline__ u16 f2bf(float f) {
    unsigned u = __float_as_uint(f);
    u += 0x7FFF + ((u >> 16) & 1);   // round-to-nearest-even
    return (u16)(u >> 16);
}

__device__ __forceinline__ void gl_lds16(const u16* g, u16* l) {
    __builtin_amdgcn_global_load_lds(
        (const __attribute__((address_space(1))) unsigned int*)g,
        (__attribute__((address_space(3))) unsigned int*)l, 16, 0, 0);
}

// ---------------- workspace layout (bytes) ----------------
#define WS_HB   0ull                                // hbuf bf16 [6144][2048]
#define WS_XG   (WS_HB + 6144ull*2048*2)            // xg bf16 [2048][512]
#define WS_WT1  (WS_XG + 2048ull*512*2)             // W1t bf16 [9][F][D]
#define WS_ME   (WS_WT1 + 9ull*2048*512*2)          // int  metaE[4096]
#define WS_MW   (WS_ME + 16384)                     // float metaW[4096]
#define WS_RT   (WS_MW + 16384)                     // int  rtok[4096]
#define WS_WROW (WS_RT + 16384)                     // float wrow[4096]
#define WS_TROW (WS_WROW + 16384)                   // int  trow[4096]
#define WS_RTG  (WS_TROW + 16384)                   // routing int[16] = offs[8],cnt[8]
#define WS_WT2  (WS_RTG + 128)                      // W2t bf16 [9][D][F]
#define WS_YB   (WS_WT2 + 9ull*2048*512*2)          // ybuf f32 [2][6144][512]
#define YS      (6144ull*512)
#define WS_NEED (WS_YB + 2ull*6144*512*4)           // ~90.4 MB (ws is 256 MiB)

// ---------------- conv unit: fp32 [R][C] 64x64 tile -> bf16 [C][R] ----------------
// float4 global reads; LDS write scatter 8-way -> 4-way via row-XOR swizzle
// (rr ^= ((col>>2)&3)<<4; bijective per column, phase-2 8-run stays contiguous).
__device__ __forceinline__ void conv_unit(int j, const float* __restrict__ srcE,
                                          const float* __restrict__ srcS,
                                          u16* __restrict__ dst,
                                          int R, int C, int shC, u16* Ls) {
    int mid = j >> 8, t2 = j & 255;
    int tr = t2 >> shC, tc = t2 & ((1 << shC) - 1);
    int r0 = tr * 64, c0 = tc * 64;
    const float* src = (mid < 8) ? srcE + (size_t)mid * R * C : srcS;
    u16* dstm = dst + (size_t)mid * R * C;
    int t = threadIdx.x;
#pragma unroll
    for (int i = 0; i < 4; ++i) {
        int rr = (t >> 4) + i * 16;
        int cc = (t & 15) * 4;
        float4v v = *(const float4v*)(src + (size_t)(r0 + rr) * C + c0 + cc);
#pragma unroll
        for (int jx = 0; jx < 4; ++jx) {
            int c = cc + jx;
            int rs = rr ^ (((c >> 2) & 3) << 4);
            Ls[c * 72 + rs] = f2bf(v[jx]);
        }
    }
    __syncthreads();
#pragma unroll
    for (int jj = 0; jj < 2; ++jj) {
        int slot = t + jj * 256;
        int cc = slot >> 3, r8 = (slot & 7) * 8;
        int r8s = r8 ^ (((cc >> 2) & 3) << 4);
        ushort8v o = *(const ushort8v*)&Ls[cc * 72 + r8s];
        *(ushort8v*)(dstm + (size_t)(c0 + cc) * R + r0 + r8) = o;
    }
}

// ---------------- gate: one wave per token (fp32 logits = np ref) ----------------
__device__ __forceinline__ void gate_wave(int t, int lane,
                                          const float* __restrict__ x,
                                          const float* __restrict__ Wg,
                                          const float* __restrict__ bg,
                                          int* __restrict__ metaE,
                                          float* __restrict__ metaW,
                                          u16* __restrict__ xg) {
    const float* xp = x + (size_t)t * DD + lane * 8;
    float4v x0 = *(const float4v*)xp;
    float4v x1 = *(const float4v*)(xp + 4);
    float xf[8] = {x0[0], x0[1], x0[2], x0[3], x1[0], x1[1], x1[2], x1[3]};
    float acc[EE] = {0.f, 0.f, 0.f, 0.f, 0.f, 0.f, 0.f, 0.f};
#pragma unroll
    for (int g = 0; g < 8; ++g) {
        const float* wp = Wg + (size_t)(lane * 8 + g) * EE;
        float4v w0 = *(const float4v*)wp;
        float4v w1 = *(const float4v*)(wp + 4);
        acc[0] += xf[g] * w0[0]; acc[1] += xf[g] * w0[1];
        acc[2] += xf[g] * w0[2]; acc[3] += xf[g] * w0[3];
        acc[4] += xf[g] * w1[0]; acc[5] += xf[g] * w1[1];
        acc[6] += xf[g] * w1[2]; acc[7] += xf[g] * w1[3];
    }
#pragma unroll
    for (int off = 1; off < 64; off <<= 1) {
#pragma unroll
        for (int e = 0; e < EE; ++e) acc[e] += __shfl_xor(acc[e], off, 64);
    }
    ushort8v xv;
#pragma unroll
    for (int jx = 0; jx < 4; ++jx) xv[jx] = f2bf(x0[jx]);
#pragma unroll
    for (int jx = 0; jx < 4; ++jx) xv[4 + jx] = f2bf(x1[jx]);
    *(ushort8v*)(xg + (size_t)t * DD + lane * 8) = xv;
    if (lane == 0) {
#pragma unroll
        for (int e = 0; e < EE; ++e) acc[e] += bg[e];
        int e0 = 0; float l0 = acc[0];
#pragma unroll
        for (int e = 1; e < EE; ++e) if (acc[e] > l0) { l0 = acc[e]; e0 = e; }
        int e1 = -1; float l1 = -3.4e38f;
#pragma unroll
        for (int e = 0; e < EE; ++e)
            if (e != e0 && acc[e] > l1) { l1 = acc[e]; e1 = e; }
        float ex = __expf(l1 - l0);
        float w0 = 1.f / (1.f + ex);
        metaE[2 * t] = e0; metaE[2 * t + 1] = e1;
        metaW[2 * t] = w0; metaW[2 * t + 1] = 1.f - w0;
    }
}

// ---------------- fused phase-1: conv1 + conv2 + gate (+ out-zero for !big) ------
__global__ __launch_bounds__(256) void fused1_k(
    const float* __restrict__ x, const float* __restrict__ Wg,
    const float* __restrict__ bg,
    const float* __restrict__ W1, const float* __restrict__ Ws1,
    const float* __restrict__ W2, const float* __restrict__ Ws2,
    float* __restrict__ out, u16* __restrict__ xg,
    u16* __restrict__ Wt1, u16* __restrict__ Wt2,
    int* __restrict__ metaE, float* __restrict__ metaW, int nconv) {
    __shared__ __align__(16) u16 Ls[64 * 72];
    int b = blockIdx.x, tid = threadIdx.x;
    if (b < nconv) {
        if (b < 2304) conv_unit(b, W1, Ws1, Wt1, DD, FF, 5, Ls);
        else          conv_unit(b - 2304, W2, Ws2, Wt2, FF, DD, 3, Ls);
    } else if (b < nconv + 512) {
        int gb = b - nconv;
        gate_wave(gb * 4 + (tid >> 6), tid & 63, x, Wg, bg, metaE, metaW, xg);
    } else {
        int zb = b - nconv - 512;
        float* op = out + (size_t)zb * 8192;
#pragma unroll
        for (int it = 0; it < 8; ++it)
            *(float4v*)(op + it * 1024 + tid * 4) = (float4v){0.f, 0.f, 0.f, 0.f};
    }
}

__global__ __launch_bounds__(256) void conv2_k(const float* __restrict__ W2,
                                               const float* __restrict__ Ws2,
                                               u16* __restrict__ Wt2) {
    __shared__ __align__(16) u16 Ls[64 * 72];
    conv_unit(blockIdx.x, W2, Ws2, Wt2, FF, DD, 3, Ls);
}

// ---------------- rank: 1 block x 256, ballot-based, 0 atomics ----------------
__global__ __launch_bounds__(256) void rank_k(const int* __restrict__ metaE,
                                              const float* __restrict__ metaW,
                                              int* __restrict__ routing,
                                              int* __restrict__ rtok,
                                              float* __restrict__ wrow,
                                              int* __restrict__ trow) {
    __shared__ __align__(16) char smem[16384];
    u16* er      = (u16*)smem;
    int* segCnt  = (int*)(smem + 8192);
    int* segBase = (int*)(smem + 10240);
    int* expTot  = (int*)(smem + 12288);
    int tid = threadIdx.x, wv = tid >> 6, lane = tid & 63;
    unsigned long long below = (lane == 0) ? 0ull : ((~0ull) >> (64 - lane));
    for (int s = wv * 16; s < wv * 16 + 16; ++s) {
        int entry = s * 64 + lane;
        int e = metaE[entry];
        int rk = 0;
#pragma unroll
        for (int ee = 0; ee < 8; ++ee) {
            unsigned long long m = __ballot(e == ee);
            if (e == ee) rk = __popcll(m & below);
            if (lane == ee) segCnt[s * 8 + ee] = __popcll(m);
        }
        er[entry] = (u16)(e | (rk << 4));
    }
    __syncthreads();
    if (tid < 8) {
        int s = 0;
        for (int g = 0; g < 64; ++g) { segBase[g * 8 + tid] = s; s += segCnt[g * 8 + tid]; }
        expTot[tid] = s;
    }
    __syncthreads();
    if (tid == 0) {
        int s = 0;
        for (int e = 0; e < 8; ++e) { int c = expTot[e]; expTot[8 + e] = s; s += c; }
    }
    __syncthreads();
    if (tid < 8) { routing[tid] = expTot[8 + tid]; routing[8 + tid] = expTot[tid]; }
    for (int i = 0; i < 16; ++i) {
        int entry = tid + i * 256;
        int v = er[entry];
        int e = v & 15, rk = v >> 4;
        int row = expTot[8 + e] + segBase[(entry >> 6) * 8 + e] + rk;
        rtok[row] = entry >> 1;
        wrow[row] = metaW[entry];
        trow[entry] = row;             // inverse map: token*2+k -> sorted row
    }
}

// ---------------- GEMM A: BM=128,BN=128,BK=64, 8 waves, dbuf 2-phase -------------
// R10 structure (best measured) with LDS-coalesced C-epilogue. Untouched.
// jobs: [0,256) shared (rt4|ct4); [256,4352): jr = (rt*16+ct)*8 + e (e=XCD pin).
__global__ __launch_bounds__(512) void gemmA_k(
    const u16* __restrict__ xg, const u16* __restrict__ Wt1,
    const float* __restrict__ b1, const float* __restrict__ bs1,
    const int* __restrict__ routing, const int* __restrict__ rtok,
    u16* __restrict__ hbuf) {
    __shared__ __align__(16) u16 SM[32768];          // 64 KB
    u16* Asb[2] = {SM, SM + 8192};                   // 2 x [128][64]
    u16* Bsb[2] = {SM + 16384, SM + 24576};          // 2 x [128][64]
    const int* offs = routing; const int* cnt = routing + 8;
    int j = blockIdx.x, tid = threadIdx.x;
    int rt, ct, Mloc, hRowBase, rowBase; bool routed;
    const u16* Bsrc; const float* bias;
    if (j < 256) {
        rt = j >> 4; ct = j & 15; Mloc = 128; rowBase = rt * 128;
        Bsrc = Wt1 + (size_t)8 * FF * DD; bias = bs1;
        hRowBase = 4096 + rt * 128; routed = false;
    } else {
        int jr = j - 256; int e = jr & 7; int rc = jr >> 3;
        rt = rc >> 4; ct = rc & 15;
        int M = cnt[e]; if (rt * 128 >= M) return;
        Mloc = M - rt * 128; if (Mloc > 128) Mloc = 128;
        rowBase = offs[e] + rt * 128;
        Bsrc = Wt1 + (size_t)e * FF * DD; bias = b1 + e * FF;
        hRowBase = rowBase; routed = true;
    }
    int n0 = ct * 128;
    int lane = tid & 63, w = tid >> 6, ln = lane & 15, quad = lane >> 4;
    int wm = w >> 2, wn = w & 3;         // 2x4 wave grid
    int lr8 = lane >> 3;
    int cs = (lane & 7) ^ lr8;           // pre-swizzled source chunk
    const u16* ApS[2];
#pragma unroll
    for (int i = 0; i < 2; ++i) {
        int r = w * 16 + i * 8 + lr8;    // 0..127
        int tok;
        if (routed) { int br = rowBase + r; if (br > 4095) br = 4095; tok = rtok[br]; }
        else tok = rowBase + r;
        ApS[i] = xg + (size_t)tok * DD + cs * 8;
    }
    const u16* BpS[2];
#pragma unroll
    for (int i = 0; i < 2; ++i) {
        int r = w * 16 + i * 8 + lr8;
        BpS[i] = Bsrc + (size_t)(n0 + r) * DD + cs * 8;
    }
    float4v acc[4][2];
#pragma unroll
    for (int a = 0; a < 4; ++a)
#pragma unroll
        for (int b = 0; b < 2; ++b) acc[a][b] = (float4v){0.f, 0.f, 0.f, 0.f};

    auto stage = [&](int kt, int pb) {
#pragma unroll
        for (int i = 0; i < 2; ++i)
            gl_lds16(ApS[i] + kt * 64, Asb[pb] + (w * 16 + i * 8) * 64);
#pragma unroll
        for (int i = 0; i < 2; ++i)
            gl_lds16(BpS[i] + kt * 64, Bsb[pb] + (w * 16 + i * 8) * 64);
    };

    stage(0, 0);
#pragma unroll
    for (int kt = 0; kt < 8; ++kt) {
        int pb = kt & 1;
        if (kt < 7) {
            stage(kt + 1, pb ^ 1);
            asm volatile("s_waitcnt vmcnt(4)" ::: "memory");
        } else {
            asm volatile("s_waitcnt vmcnt(0)" ::: "memory");
        }
        __builtin_amdgcn_s_barrier();
        __builtin_amdgcn_sched_barrier(0);
        const u16* Ab = Asb[pb]; const u16* Bb = Bsb[pb];
#pragma unroll
        for (int s = 0; s < 2; ++s) {
            int chs = ((s * 4 + quad) ^ (ln & 7)) * 8;
            short8 Af[4], Bf[2];
#pragma unroll
            for (int a = 0; a < 4; ++a) {
                int ra = wm * 64 + a * 16 + ln;
                Af[a] = *(const short8*)(Ab + ra * 64 + chs);
            }
#pragma unroll
            for (int b = 0; b < 2; ++b) {
                int rb = wn * 32 + b * 16 + ln;
                Bf[b] = *(const short8*)(Bb + rb * 64 + chs);
            }
#pragma unroll
            for (int a = 0; a < 4; ++a)
#pragma unroll
                for (int b = 0; b < 2; ++b)
                    acc[a][b] = __builtin_amdgcn_mfma_f32_16x16x32_bf16(Af[a], Bf[b], acc[a][b], 0, 0, 0);
        }
        __builtin_amdgcn_sched_barrier(0);
        __builtin_amdgcn_s_barrier();
    }
    // ---- LDS-coalesced epilogue: acc -> Cs[128][136] -> 256B-row stores ----
    __syncthreads();                     // all LDS reads of As/Bs done
    u16* Cs = SM;                        // 128*136 u16 = 34.8 KB (dead buffers)
#pragma unroll
    for (int b = 0; b < 2; ++b) {
        int n = wn * 32 + b * 16 + ln;
        float bv = bias[n0 + n];
#pragma unroll
        for (int a = 0; a < 4; ++a) {
#pragma unroll
            for (int i = 0; i < 4; ++i) {
                int lr = wm * 64 + a * 16 + quad * 4 + i;
                float v = acc[a][b][i] + bv;
                v = v > 0.f ? v : 0.f;
                Cs[lr * 136 + n] = f2bf(v);
            }
        }
    }
    __syncthreads();
#pragma unroll
    for (int p = 0; p < 4; ++p) {
        int idx = p * 512 + tid;         // 2048 chunks of 16B
        int row = idx >> 4, ch = idx & 15;
        if (row < Mloc) {
            ushort8v o = *(const ushort8v*)(Cs + row * 136 + ch * 8);
            *(ushort8v*)(hbuf + (size_t)(hRowBase + row) * FF + n0 + ch * 8) = o;
        }
    }
}

// ---------------- GEMM B (big): BM=128,BN=128,BK=64, K-split x2, NO atomics ------
// R10 version (384 active blocks; R11 showed no-ksplit starves the machine).
// jobs: [0,128) shared (rt4|ct2|ks1); [128,2176): jr = ((rt*4+ct)*2+ks)*8 + e.
__global__ __launch_bounds__(512) void gemmB_k(
    const u16* __restrict__ hbuf, const u16* __restrict__ Wt2,
    const float* __restrict__ b2, const float* __restrict__ bs2,
    const int* __restrict__ routing, float* __restrict__ ybuf) {
    __shared__ __align__(16) u16 As[2][128 * 64];    // 2 x 16 KB
    __shared__ __align__(16) u16 Bs[2][128 * 64];    // 2 x 16 KB
    const int* offs = routing; const int* cnt = routing + 8;
    int j = blockIdx.x, tid = threadIdx.x;
    int rt, ct, ks, Mloc, aRowBase;
    const u16* Bsrc; const float* bias;
    if (j < 128) {
        ks = j & 1; ct = (j >> 1) & 3; rt = j >> 3;
        Mloc = 128; aRowBase = 4096 + rt * 128;
        Bsrc = Wt2 + (size_t)8 * DD * FF; bias = bs2;
    } else {
        int jr = j - 128; int e = jr & 7; int rc = jr >> 3;
        ks = rc & 1; ct = (rc >> 1) & 3; rt = rc >> 3;
        int M = cnt[e]; if (rt * 128 >= M) return;
        Mloc = M - rt * 128; if (Mloc > 128) Mloc = 128;
        aRowBase = offs[e] + rt * 128;
        Bsrc = Wt2 + (size_t)e * DD * FF; bias = b2 + e * DD;
    }
    int n0 = ct * 128;
    int lane = tid & 63, w = tid >> 6, ln = lane & 15, quad = lane >> 4;
    int wm = w >> 2, wn = w & 3;
    int lr8 = lane >> 3;
    int cs = (lane & 7) ^ lr8;
    const u16* ApS[2];
#pragma unroll
    for (int i = 0; i < 2; ++i) {
        int r = w * 16 + i * 8 + lr8;
        ApS[i] = hbuf + (size_t)(aRowBase + r) * FF + ks * 1024 + cs * 8;
    }
    const u16* BpS[2];
#pragma unroll
    for (int i = 0; i < 2; ++i) {
        int r = w * 16 + i * 8 + lr8;
        BpS[i] = Bsrc + (size_t)(n0 + r) * FF + ks * 1024 + cs * 8;
    }
    float4v acc[4][2];
#pragma unroll
    for (int a = 0; a < 4; ++a)
#pragma unroll
        for (int b = 0; b < 2; ++b) acc[a][b] = (float4v){0.f, 0.f, 0.f, 0.f};

    auto stage = [&](int kt, int pb) {
#pragma unroll
        for (int i = 0; i < 2; ++i)
            gl_lds16(ApS[i] + kt * 64, &As[pb][0] + (w * 16 + i * 8) * 64);
#pragma unroll
        for (int i = 0; i < 2; ++i)
            gl_lds16(BpS[i] + kt * 64, &Bs[pb][0] + (w * 16 + i * 8) * 64);
    };

    stage(0, 0);
#pragma unroll
    for (int kt = 0; kt < 16; ++kt) {
        int pb = kt & 1;
        if (kt < 15) {
            stage(kt + 1, pb ^ 1);
            asm volatile("s_waitcnt vmcnt(4)" ::: "memory");
        } else {
            asm volatile("s_waitcnt vmcnt(0)" ::: "memory");
        }
        __builtin_amdgcn_s_barrier();
        __builtin_amdgcn_sched_barrier(0);
        const u16* Ab = &As[pb][0]; const u16* Bb = &Bs[pb][0];
#pragma unroll
        for (int s = 0; s < 2; ++s) {
            int chs = ((s * 4 + quad) ^ (ln & 7)) * 8;
            short8 Af[4], Bf[2];
#pragma unroll
            for (int a = 0; a < 4; ++a) {
                int ra = wm * 64 + a * 16 + ln;
                Af[a] = *(const short8*)(Ab + ra * 64 + chs);
            }
#pragma unroll
            for (int b = 0; b < 2; ++b) {
                int rb = wn * 32 + b * 16 + ln;
                Bf[b] = *(const short8*)(Bb + rb * 64 + chs);
            }
#pragma unroll
            for (int a = 0; a < 4; ++a)
#pragma unroll
                for (int b = 0; b < 2; ++b)
                    acc[a][b] = __builtin_amdgcn_mfma_f32_16x16x32_bf16(Af[a], Bf[b], acc[a][b], 0, 0, 0);
        }
        __builtin_amdgcn_sched_barrier(0);
        __builtin_amdgcn_s_barrier();
    }
    float* yb = ybuf + (size_t)ks * YS;
#pragma unroll
    for (int b = 0; b < 2; ++b) {
        int n = n0 + wn * 32 + b * 16 + ln;
        float bv = (ks == 0) ? bias[n] : 0.f;
#pragma unroll
        for (int a = 0; a < 4; ++a) {
#pragma unroll
            for (int i = 0; i < 4; ++i) {
                int lr = wm * 64 + a * 16 + quad * 4 + i;
                if (lr < Mloc)
                    yb[(size_t)(aRowBase + lr) * DD + n] = acc[a][b][i] + bv;
            }
        }
    }
}

// ---------------- combine: out[t] = w0*(y0a+y0b) + w1*(y1a+y1b) + 0.5*(ysa+ysb) --
__global__ __launch_bounds__(256) void combine_k(
    const float* __restrict__ ybuf, const int* __restrict__ trow,
    const float* __restrict__ metaW, float* __restrict__ out) {
    int tid = threadIdx.x;
    int tok = blockIdx.x * 2 + (tid >> 7);
    int q = (tid & 127) * 4;
    int r0 = trow[2 * tok], r1 = trow[2 * tok + 1];
    float w0 = metaW[2 * tok], w1 = metaW[2 * tok + 1];
    const float* ya = ybuf;
    const float* yb = ybuf + YS;
    float4v y0a = *(const float4v*)(ya + (size_t)r0 * DD + q);
    float4v y0b = *(const float4v*)(yb + (size_t)r0 * DD + q);
    float4v y1a = *(const float4v*)(ya + (size_t)r1 * DD + q);
    float4v y1b = *(const float4v*)(yb + (size_t)r1 * DD + q);
    float4v ysa = *(const float4v*)(ya + (size_t)(4096 + tok) * DD + q);
    float4v ysb = *(const float4v*)(yb + (size_t)(4096 + tok) * DD + q);
    float4v o;
#pragma unroll
    for (int i = 0; i < 4; ++i)
        o[i] = w0 * (y0a[i] + y0b[i]) + w1 * (y1a[i] + y1b[i]) + 0.5f * (ysa[i] + ysb[i]);
    *(float4v*)(out + (size_t)tok * DD + q) = o;
}

// ---------------- GEMM B (!big fallback): K-split x2, pipelined, atomics --------
__global__ __launch_bounds__(256) void gemmBat_k(
    const u16* __restrict__ hbuf, const u16* __restrict__ Wt2,
    const float* __restrict__ b2, const float* __restrict__ bs2,
    const int* __restrict__ routing, const int* __restrict__ rtok,
    const float* __restrict__ wrow, float* __restrict__ out) {
    __shared__ __align__(16) u16 As[2][64 * 64];
    __shared__ __align__(16) u16 Bs[2][128 * 64];
    const int* offs = routing; const int* cnt = routing + 8;
    int j = blockIdx.x, tid = threadIdx.x;
    int rt, ct, ks, Mloc, aRowBase; bool sh;
    const u16* Bsrc; const float* bias;
    if (j < 256) {
        sh = true; rt = j >> 3; int sub = j & 7; ct = sub >> 1; ks = sub & 1;
        Mloc = 64; aRowBase = 4096 + rt * 64;
        Bsrc = Wt2 + (size_t)8 * DD * FF; bias = bs2;
    } else {
        sh = false; int jr = j - 256; int e = jr & 7; int rc = jr >> 3;
        rt = rc >> 3; ct = (rc >> 1) & 3; ks = rc & 1;
        int M = cnt[e]; if (rt * 64 >= M) return;
        Mloc = M - rt * 64; if (Mloc > 64) Mloc = 64;
        aRowBase = offs[e] + rt * 64;
        Bsrc = Wt2 + (size_t)e * DD * FF; bias = b2 + e * DD;
    }
    int n0 = ct * 128;
    int lane = tid & 63, w = tid >> 6, ln = lane & 15, quad = lane >> 4;
    int lr8 = lane >> 3;
    int cs = (lane & 7) ^ lr8;
    const u16* ApS[2];
#pragma unroll
    for (int i = 0; i < 2; ++i) {
        int r = w * 16 + i * 8 + lr8;
        ApS[i] = hbuf + (size_t)(aRowBase + r) * FF + ks * 1024 + cs * 8;
    }
    const u16* BpS[4];
#pragma unroll
    for (int i = 0; i < 4; ++i) {
        int r = w * 32 + i * 8 + lr8;
        BpS[i] = Bsrc + (size_t)(n0 + r) * FF + ks * 1024 + cs * 8;
    }
    float4v acc[2][4];
#pragma unroll
    for (int a = 0; a < 2; ++a)
#pragma unroll
        for (int b = 0; b < 4; ++b) acc[a][b] = (float4v){0.f, 0.f, 0.f, 0.f};
    auto stage = [&](int kt, int pb) {
        u16* Ab = &As[pb][0]; u16* Bb = &Bs[pb][0];
#pragma unroll
        for (int i = 0; i < 2; ++i)
            gl_lds16(ApS[i] + kt * 64, Ab + (w * 16 + i * 8) * 64);
#pragma unroll
        for (int i = 0; i < 4; ++i)
            gl_lds16(BpS[i] + kt * 64, Bb + (w * 32 + i * 8) * 64);
    };
    stage(0, 0);
#pragma unroll
    for (int kt = 0; kt < 16; ++kt) {
        int pb = kt & 1;
        if (kt < 15) {
            stage(kt + 1, pb ^ 1);
            asm volatile("s_waitcnt vmcnt(6)" ::: "memory");
        } else {
            asm volatile("s_waitcnt vmcnt(0)" ::: "memory");
        }
        __builtin_amdgcn_s_barrier();
        __builtin_amdgcn_sched_barrier(0);
        const u16* Ab = &As[pb][0]; const u16* Bb = &Bs[pb][0];
#pragma unroll
        for (int s = 0; s < 2; ++s) {
            int chs = ((s * 4 + quad) ^ (ln & 7)) * 8;
            short8 Af[2], Bf[4];
#pragma unroll
            for (int a = 0; a < 2; ++a) {
                int ra = (w & 1) * 32 + a * 16 + ln;
                Af[a] = *(const short8*)(Ab + ra * 64 + chs);
            }
#pragma unroll
            for (int b = 0; b < 4; ++b) {
                int rb = (w >> 1) * 64 + b * 16 + ln;
                Bf[b] = *(const short8*)(Bb + rb * 64 + chs);
            }
#pragma unroll
            for (int a = 0; a < 2; ++a)
#pragma unroll
                for (int b = 0; b < 4; ++b)
                    acc[a][b] = __builtin_amdgcn_mfma_f32_16x16x32_bf16(Af[a], Bf[b], acc[a][b], 0, 0, 0);
        }
        __builtin_amdgcn_sched_barrier(0);
        __builtin_amdgcn_s_barrier();
    }
    float bv[4];
#pragma unroll
    for (int b = 0; b < 4; ++b)
        bv[b] = (ks == 0) ? bias[n0 + (w >> 1) * 64 + b * 16 + ln] : 0.f;
#pragma unroll
    for (int a = 0; a < 2; ++a) {
#pragma unroll
        for (int i = 0; i < 4; ++i) {
            int lr = (w & 1) * 32 + a * 16 + quad * 4 + i;
            if (lr < Mloc) {
                int row = aRowBase + lr;
                int t; float wr;
                if (sh) { t = row - 4096; wr = 0.5f; }
                else    { t = rtok[row]; wr = wrow[row]; }
                float* op = out + (size_t)t * DD;
#pragma unroll
                for (int b = 0; b < 4; ++b) {
                    int n = n0 + (w >> 1) * 64 + b * 16 + ln;
                    atomicAdd(op + n, wr * (acc[a][b][i] + bv[b]));
                }
            }
        }
    }
}

// ---------------- launcher ----------------
extern "C" void kernel_launch(void* const* d_in, const int* in_sizes, int n_in,
                              void* d_out, int out_size, void* d_ws, size_t ws_size,
                              hipStream_t stream) {
    const float* x   = (const float*)d_in[0];
    const float* Wg  = (const float*)d_in[1];
    const float* bg  = (const float*)d_in[2];
    const float* W1  = (const float*)d_in[3];
    const float* b1  = (const float*)d_in[4];
    const float* W2  = (const float*)d_in[5];
    const float* b2  = (const float*)d_in[6];
    const float* Ws1 = (const float*)d_in[7];
    const float* bs1 = (const float*)d_in[8];
    const float* Ws2 = (const float*)d_in[9];
    const float* bs2 = (const float*)d_in[10];
    float* out = (float*)d_out;

    char* ws = (char*)d_ws;
    u16*   hbuf    = (u16*)(ws + WS_HB);
    u16*   xg      = (u16*)(ws + WS_XG);
    u16*   Wt1     = (u16*)(ws + WS_WT1);
    int*   metaE   = (int*)(ws + WS_ME);
    float* metaW   = (float*)(ws + WS_MW);
    int*   rtok    = (int*)(ws + WS_RT);
    float* wrow    = (float*)(ws + WS_WROW);
    int*   trow    = (int*)(ws + WS_TROW);
    int*   routing = (int*)(ws + WS_RTG);
    bool   big     = ws_size >= WS_NEED;
    u16*   Wt2     = big ? (u16*)(ws + WS_WT2) : Wt1;
    float* ybuf    = (float*)(ws + WS_YB);
    int    nconv   = big ? 4608 : 2304;
    int    ngrid1  = big ? (nconv + 512) : (nconv + 640); // zero-jobs only if atomics

    fused1_k<<<ngrid1, 256, 0, stream>>>(x, Wg, bg, W1, Ws1, W2, Ws2,
                                         out, xg, Wt1, Wt2, metaE, metaW, nconv);
    rank_k<<<1, 256, 0, stream>>>(metaE, metaW, routing, rtok, wrow, trow);
    gemmA_k<<<4352, 512, 0, stream>>>(xg, Wt1, b1, bs1, routing, rtok, hbuf);
    if (big) {
        gemmB_k<<<2176, 512, 0, stream>>>(hbuf, Wt2, b2, bs2, routing, ybuf);
        combine_k<<<1024, 256, 0, stream>>>(ybuf, trow, metaW, out);
    } else {
        conv2_k<<<2304, 256, 0, stream>>>(W2, Ws2, Wt2);
        gemmBat_k<<<4352, 256, 0, stream>>>(hbuf, Wt2, b2, bs2, routing, rtok, wrow, out);
    }
}